// Round 1
// baseline (360.328 us; speedup 1.0000x reference)
//
#include <hip/hip_runtime.h>
#include <hip/hip_bf16.h>

// Problem constants (B=8,S=4096,D=1024, A=16, C=8, dc=64, apc=2)
#define DIM 1024
#define NANCH 16
#define NCOMP 8
#define DC 64
#define DC2 128
#define EPS_LN 1e-5f
#define EPS_NORM 1e-12f

typedef __bf16 bf16x8 __attribute__((ext_vector_type(8)));
typedef float f32x4 __attribute__((ext_vector_type(4)));

// ---------------- Kernel 1: normalize anchors -> f32 ----------------
__global__ __launch_bounds__(256) void knorm_anchors(
    const float* __restrict__ anchors, float* __restrict__ An) {
  int a = blockIdx.x, t = threadIdx.x;
  int lane = t & 63, wid = t >> 6;
  __shared__ float red[4];
  float v[4]; float ss = 0.f;
#pragma unroll
  for (int i = 0; i < 4; i++) {
    v[i] = anchors[a * DIM + t + 256 * i];
    ss += v[i] * v[i];
  }
  for (int off = 32; off; off >>= 1) ss += __shfl_down(ss, off);
  if (lane == 0) red[wid] = ss;
  __syncthreads();
  float inv = 1.f / fmaxf(sqrtf(red[0] + red[1] + red[2] + red[3]), EPS_NORM);
#pragma unroll
  for (int i = 0; i < 4; i++) An[a * DIM + t + 256 * i] = v[i] * inv;
}

// ------- Kernel 2: transpose Wp (512x1024 f32) -> WpT (1024x512 bf16) ----
__global__ __launch_bounds__(256) void ktrans(
    const float* __restrict__ Wp, __hip_bfloat16* __restrict__ WpT) {
  __shared__ float tile[64][65];
  int bj = blockIdx.x, bk = blockIdx.y;  // grid (16, 8)
  int tx = threadIdx.x & 63, ty = threadIdx.x >> 6;
#pragma unroll
  for (int i = 0; i < 16; i++) {
    int r = ty + 4 * i;  // local k
    tile[r][tx] = Wp[(size_t)(bk * 64 + r) * DIM + bj * 64 + tx];
  }
  __syncthreads();
#pragma unroll
  for (int i = 0; i < 16; i++) {
    int r = ty + 4 * i;  // local j
    WpT[(size_t)(bj * 64 + r) * 512 + bk * 64 + tx] = __float2bfloat16(tile[tx][r]);
  }
}

// --- Kernel 2b: build B-fragment tables for W2 and An (bf16) -------------
// W2B[((k*4+nt)*4+ks)*512 + lane*8 + j] = W2[k][e=ks*32+(lane>>4)*8+j][n=nt*16+(lane&15)]
// AnB[ks*512 + lane*8 + j]             = An[a=lane&15][e=ks*32+(lane>>4)*8+j]
__global__ __launch_bounds__(256) void kprep(
    const float* __restrict__ W2, const float* __restrict__ An,
    __hip_bfloat16* __restrict__ W2B, __hip_bfloat16* __restrict__ AnB) {
  int id = blockIdx.x * 256 + threadIdx.x;
  if (id < 65536) {
    int j = id & 7, lane = (id >> 3) & 63, ks = (id >> 9) & 3,
        nt = (id >> 11) & 3, k = id >> 13;
    int e = ks * 32 + (lane >> 4) * 8 + j;
    int n = nt * 16 + (lane & 15);
    W2B[id] = __float2bfloat16(W2[k * (DC2 * DC) + e * DC + n]);
  } else {
    int id2 = id - 65536;  // 16384 elems
    int j = id2 & 7, lane = (id2 >> 3) & 63, ks = id2 >> 9;  // ks in [0,32)
    int e = ks * 32 + (lane >> 4) * 8 + j;
    int a = lane & 15;
    AnB[id2] = __float2bfloat16(An[a * DIM + e]);
  }
}

// ---------------- Kernel 3: 8 tokens/block -> y (N x 512 bf16) ----------
// 8 tokens/block (not 16): LDS 21.1 KB -> 7 blocks/CU = 28 waves/CU (was
// 38.4 KB -> 4 blocks = 16 waves). MFMA runs with duplicated A rows 8-15
// (row index clamped l15&7); outputs for rows >= 8 are discarded.
// Phase A: LN + l2norm -> h (bf16, LDS), 2 tokens/wave, float4 loads.
// Phase B: tri = 1 - h@AnT via MFMA. Phase C: u = relu(...)^2 (overwrites
// h in LDS). Phase D: per-comp y = u@W2 + b2 + LN(dc=64) -> yout.
#define LDA_H 1032  // 1024 + 8 bf16 pad: row stride 2064 B = 516 dw, 516%32=4
__global__ __launch_bounds__(256, 7) void ktoken(
    const float* __restrict__ x, const __hip_bfloat16* __restrict__ AnB,
    const float* __restrict__ ln_g, const float* __restrict__ ln_b,
    const float* __restrict__ W1, const float* __restrict__ b1,
    const __hip_bfloat16* __restrict__ W2B, const float* __restrict__ b2,
    const float* __restrict__ cg, const float* __restrict__ cb,
    __hip_bfloat16* __restrict__ yout) {
  int t = threadIdx.x;
  int lane = t & 63, w = t >> 6;
  int l15 = lane & 15, quad = lane >> 4;
  int n0 = blockIdx.x * 8;

  __shared__ __hip_bfloat16 hu[8 * LDA_H];  // 16.5 KB: h, then u
  __shared__ float tri_s[8 * 16];           // [token][anchor]
  __shared__ float part[4 * 64 * 4];        // tri partial tiles

  // ---- Phase A: LN + l2norm for tokens w*2, w*2+1 (one wave each) ----
  // element mapping: lane holds elements i*256 + lane*4 + j (float4 loads)
  float gv[16], bv[16];
#pragma unroll
  for (int i = 0; i < 4; i++) {
    f32x4 g4 = *(const f32x4*)(&ln_g[i * 256 + lane * 4]);
    f32x4 b4 = *(const f32x4*)(&ln_b[i * 256 + lane * 4]);
#pragma unroll
    for (int j = 0; j < 4; j++) { gv[i * 4 + j] = g4[j]; bv[i * 4 + j] = b4[j]; }
  }
#pragma unroll
  for (int it = 0; it < 2; it++) {
    int tok = w * 2 + it;
    const float* xr = x + (size_t)(n0 + tok) * DIM;
    float xv[16], s = 0.f, s2 = 0.f;
#pragma unroll
    for (int i = 0; i < 4; i++) {
      f32x4 v4 = *(const f32x4*)(&xr[i * 256 + lane * 4]);
#pragma unroll
      for (int j = 0; j < 4; j++) {
        float v = v4[j];
        xv[i * 4 + j] = v; s += v; s2 += v * v;
      }
    }
#pragma unroll
    for (int off = 32; off; off >>= 1) { s += __shfl_xor(s, off); s2 += __shfl_xor(s2, off); }
    float mu = s * (1.f / DIM);
    float rstd = rsqrtf(s2 * (1.f / DIM) - mu * mu + EPS_LN);
    float ss = 0.f;
#pragma unroll
    for (int i = 0; i < 16; i++) {
      float h = (xv[i] - mu) * rstd * gv[i] + bv[i];
      xv[i] = h; ss += h * h;
    }
#pragma unroll
    for (int off = 32; off; off >>= 1) ss += __shfl_xor(ss, off);
    float inv = 1.f / fmaxf(sqrtf(ss), EPS_NORM);
#pragma unroll
    for (int i = 0; i < 4; i++) {
      union { uint2 u; __hip_bfloat16 h[4]; } pk;
#pragma unroll
      for (int j = 0; j < 4; j++) pk.h[j] = __float2bfloat16(xv[i * 4 + j] * inv);
      *(uint2*)(&hu[tok * LDA_H + i * 256 + lane * 4]) = pk.u;
    }
  }
  __syncthreads();

  // ---- Phase B: tri[m][a] = 1 - sum_e h[m][e]*An[a][e], MFMA over K=1024 ----
  {
    f32x4 tacc = {0.f, 0.f, 0.f, 0.f};
    int ar = l15 & 7;  // clamp A rows: tokens 8-15 duplicate 0-7, outputs unused
#pragma unroll
    for (int ks = w * 8; ks < w * 8 + 8; ks++) {
      bf16x8 afr = *(const bf16x8*)(&hu[ar * LDA_H + ks * 32 + quad * 8]);
      bf16x8 bfr = *(const bf16x8*)(&AnB[ks * 512 + lane * 8]);
      tacc = __builtin_amdgcn_mfma_f32_16x16x32_bf16(afr, bfr, tacc, 0, 0, 0);
    }
    *(f32x4*)(&part[(w * 64 + lane) * 4]) = tacc;
  }
  __syncthreads();
  {
    int ln = t & 63, rg = t >> 6;
    float v = part[(0 * 64 + ln) * 4 + rg] + part[(1 * 64 + ln) * 4 + rg] +
              part[(2 * 64 + ln) * 4 + rg] + part[(3 * 64 + ln) * 4 + rg];
    int m = (ln >> 4) * 4 + rg, a = ln & 15;
    if (m < 8) tri_s[m * 16 + a] = 1.f - v;
  }
  __syncthreads();

  // ---- Phase C: u = relu(tri0*W1a + tri1*W1b + b1)^2 -> hu (bf16) ----
  {
    float w1a[4], w1b[4], b1v[4];
#pragma unroll
    for (int i = 0; i < 4; i++) {
      int idx = i * 256 + t, k = idx >> 7, e = idx & 127;
      w1a[i] = W1[k * 256 + e];
      w1b[i] = W1[k * 256 + 128 + e];
      b1v[i] = b1[idx];
    }
#pragma unroll
    for (int tok = 0; tok < 8; tok++) {
#pragma unroll
      for (int i = 0; i < 4; i++) {
        int idx = i * 256 + t, k = idx >> 7;
        float uu = tri_s[tok * 16 + k] * w1a[i] +
                   tri_s[tok * 16 + 8 + k] * w1b[i] + b1v[i];
        uu = fmaxf(uu, 0.f);
        hu[tok * LDA_H + idx] = __float2bfloat16(uu * uu);
      }
    }
  }
  __syncthreads();

  // ---- Phase D: per-comp y = u@W2 + b2, LN over dc=64, write ----
  // wave w handles comps 2w, 2w+1
#pragma unroll
  for (int kc = 0; kc < 2; kc++) {
    int k = w * 2 + kc;
    int ar = l15 & 7;
    bf16x8 afr[4];
#pragma unroll
    for (int ks = 0; ks < 4; ks++)
      afr[ks] = *(const bf16x8*)(&hu[ar * LDA_H + k * 128 + ks * 32 + quad * 8]);
    f32x4 acc[4] = {{0,0,0,0},{0,0,0,0},{0,0,0,0},{0,0,0,0}};
#pragma unroll
    for (int nt = 0; nt < 4; nt++) {
#pragma unroll
      for (int ks = 0; ks < 4; ks++) {
        bf16x8 bfr = *(const bf16x8*)(&W2B[(size_t)(((k * 4 + nt) * 4 + ks)) * 512 + lane * 8]);
        acc[nt] = __builtin_amdgcn_mfma_f32_16x16x32_bf16(afr[ks], bfr, acc[nt], 0, 0, 0);
      }
    }
    // add b2, LN over 64 (token m = quad*4+reg; its 64 vals live in this quad)
    float vals[4][4], s1[4] = {0,0,0,0}, s2[4] = {0,0,0,0};
#pragma unroll
    for (int nt = 0; nt < 4; nt++) {
      float b2v = b2[k * 64 + nt * 16 + l15];
#pragma unroll
      for (int r = 0; r < 4; r++) {
        float v = acc[nt][r] + b2v;
        vals[nt][r] = v; s1[r] += v; s2[r] += v * v;
      }
    }
#pragma unroll
    for (int r = 0; r < 4; r++) {
#pragma unroll
      for (int off = 1; off < 16; off <<= 1) {
        s1[r] += __shfl_xor(s1[r], off);
        s2[r] += __shfl_xor(s2[r], off);
      }
    }
#pragma unroll
    for (int r = 0; r < 4; r++) {
      float mu = s1[r] * (1.f / DC);
      float rs = rsqrtf(s2[r] * (1.f / DC) - mu * mu + EPS_LN);
      int tokrow = quad * 4 + r;
      if (tokrow < 8) {
#pragma unroll
        for (int nt = 0; nt < 4; nt++) {
          int d = nt * 16 + l15;
          float yn = (vals[nt][r] - mu) * rs * cg[k * 64 + d] + cb[k * 64 + d];
          yout[(size_t)(n0 + tokrow) * 512 + k * 64 + d] = __float2bfloat16(yn);
        }
      }
    }
  }
}

// ---------------- Kernel 4: out = x + sig(gate)*(y @ Wp + bp) -----------
#define LDP 72
__global__ __launch_bounds__(256) void kgemm(
    const __hip_bfloat16* __restrict__ Y, const __hip_bfloat16* __restrict__ WpT,
    const float* __restrict__ x, const float* __restrict__ bp,
    const float* __restrict__ gate, float* __restrict__ out) {
  __shared__ alignas(16) __hip_bfloat16 As[128 * LDP];
  __shared__ alignas(16) __hip_bfloat16 Bs[128 * LDP];
  int t = threadIdx.x, lane = t & 63, wid = t >> 6;
  int bm = blockIdx.x, bj = blockIdx.y;
  int wm = (wid >> 1) * 64, wj = (wid & 1) * 64;
  int l15 = lane & 15, quad = lane >> 4;

  f32x4 acc[4][4] = {};

  for (int k0 = 0; k0 < 512; k0 += 64) {
#pragma unroll
    for (int it = 0; it < 4; it++) {
      int c = it * 256 + t;
      int row = c >> 3, col = (c & 7) * 8;
      *(uint4*)(&As[row * LDP + col]) =
          *(const uint4*)(&Y[(size_t)(bm * 128 + row) * 512 + k0 + col]);
      *(uint4*)(&Bs[row * LDP + col]) =
          *(const uint4*)(&WpT[(size_t)(bj * 128 + row) * 512 + k0 + col]);
    }
    __syncthreads();
#pragma unroll
    for (int kk = 0; kk < 64; kk += 32) {
      bf16x8 af[4], bfr[4];
#pragma unroll
      for (int i = 0; i < 4; i++) {
        af[i]  = *(const bf16x8*)(&As[(wm + i * 16 + l15) * LDP + kk + quad * 8]);
        bfr[i] = *(const bf16x8*)(&Bs[(wj + i * 16 + l15) * LDP + kk + quad * 8]);
      }
#pragma unroll
      for (int i = 0; i < 4; i++)
#pragma unroll
        for (int j = 0; j < 4; j++)
          acc[i][j] = __builtin_amdgcn_mfma_f32_16x16x32_bf16(af[i], bfr[j], acc[i][j], 0, 0, 0);
    }
    __syncthreads();
  }

  float sg[4], bpv[4];
#pragma unroll
  for (int j = 0; j < 4; j++) {
    int gc = bj * 128 + wj + j * 16 + l15;
    sg[j] = 1.f / (1.f + expf(-gate[gc]));
    bpv[j] = bp[gc];
  }
#pragma unroll
  for (int i = 0; i < 4; i++) {
#pragma unroll
    for (int j = 0; j < 4; j++) {
      int gc = bj * 128 + wj + j * 16 + l15;
#pragma unroll
      for (int r = 0; r < 4; r++) {
        int gr = bm * 128 + wm + i * 16 + quad * 4 + r;   // D row=(lane>>4)*4+reg
        size_t idx = (size_t)gr * DIM + gc;
        out[idx] = x[idx] + sg[j] * (acc[i][j][r] + bpv[j]);
      }
    }
  }
}

extern "C" void kernel_launch(void* const* d_in, const int* in_sizes, int n_in,
                              void* d_out, int out_size, void* d_ws, size_t ws_size,
                              hipStream_t stream) {
  const float* x       = (const float*)d_in[0];
  const float* anchors = (const float*)d_in[1];
  const float* ln_g    = (const float*)d_in[2];
  const float* ln_b    = (const float*)d_in[3];
  const float* W1      = (const float*)d_in[4];
  const float* b1      = (const float*)d_in[5];
  const float* W2      = (const float*)d_in[6];
  const float* b2      = (const float*)d_in[7];
  const float* cg      = (const float*)d_in[8];
  const float* cb      = (const float*)d_in[9];
  const float* Wp      = (const float*)d_in[10];
  const float* bp      = (const float*)d_in[11];
  const float* gate    = (const float*)d_in[12];

  int N = in_sizes[0] / DIM;  // 32768 tokens

  char* w = (char*)d_ws;
  size_t off = 0;
  float* An           = (float*)(w + off);           off += 64 << 10;   // 64 KB
  __hip_bfloat16* WpT = (__hip_bfloat16*)(w + off);  off += 1 << 20;    // 1 MB
  __hip_bfloat16* W2B = (__hip_bfloat16*)(w + off);  off += 128 << 10;  // 128 KB
  __hip_bfloat16* AnB = (__hip_bfloat16*)(w + off);  off += 32 << 10;   // 32 KB
  __hip_bfloat16* Yb  = (__hip_bfloat16*)(w + off);                     // N*512*2 = 32 MB

  knorm_anchors<<<NANCH, 256, 0, stream>>>(anchors, An);
  ktrans<<<dim3(16, 8), 256, 0, stream>>>(Wp, WpT);
  kprep<<<320, 256, 0, stream>>>(W2, An, W2B, AnB);
  ktoken<<<N / 8, 256, 0, stream>>>(x, AnB, ln_g, ln_b, W1, b1, W2B, b2, cg, cb, Yb);
  kgemm<<<dim3(N / 128, DIM / 128), 256, 0, stream>>>(Yb, WpT, x, bp, gate,
                                                      (float*)d_out);
}

// Round 2
// 354.953 us; speedup vs baseline: 1.0151x; 1.0151x over previous
//
#include <hip/hip_runtime.h>
#include <hip/hip_bf16.h>

// Problem constants (B=8,S=4096,D=1024, A=16, C=8, dc=64, apc=2)
#define DIM 1024
#define NANCH 16
#define NCOMP 8
#define DC 64
#define DC2 128
#define EPS_LN 1e-5f
#define EPS_NORM 1e-12f

typedef __bf16 bf16x8 __attribute__((ext_vector_type(8)));
typedef float f32x4 __attribute__((ext_vector_type(4)));

// ---- DPP rotate-reduce helpers: sum over 16-lane row, result in all lanes.
// v_add_f32_dpp row_ror:{1,2,4,8} — VALU pipe only, zero DS ops.
template <int CTRL>
__device__ __forceinline__ float rr_add(float v) {
  return v + __int_as_float(__builtin_amdgcn_update_dpp(
                 0, __float_as_int(v), CTRL, 0xF, 0xF, true));
}
__device__ __forceinline__ float rowsum16(float v) {
  v = rr_add<0x121>(v);  // row_ror:1
  v = rr_add<0x122>(v);  // row_ror:2
  v = rr_add<0x124>(v);  // row_ror:4
  v = rr_add<0x128>(v);  // row_ror:8
  return v;
}
__device__ __forceinline__ float wavesum64(float v) {
  v = rowsum16(v);
  v += __shfl_xor(v, 16);
  v += __shfl_xor(v, 32);
  return v;
}

// ---------------- Kernel 1: normalize anchors -> f32 ----------------
__global__ __launch_bounds__(256) void knorm_anchors(
    const float* __restrict__ anchors, float* __restrict__ An) {
  int a = blockIdx.x, t = threadIdx.x;
  int lane = t & 63, wid = t >> 6;
  __shared__ float red[4];
  float v[4]; float ss = 0.f;
#pragma unroll
  for (int i = 0; i < 4; i++) {
    v[i] = anchors[a * DIM + t + 256 * i];
    ss += v[i] * v[i];
  }
  for (int off = 32; off; off >>= 1) ss += __shfl_down(ss, off);
  if (lane == 0) red[wid] = ss;
  __syncthreads();
  float inv = 1.f / fmaxf(sqrtf(red[0] + red[1] + red[2] + red[3]), EPS_NORM);
#pragma unroll
  for (int i = 0; i < 4; i++) An[a * DIM + t + 256 * i] = v[i] * inv;
}

// ------- Kernel 2: transpose Wp (512x1024 f32) -> WpT (1024x512 bf16) ----
__global__ __launch_bounds__(256) void ktrans(
    const float* __restrict__ Wp, __hip_bfloat16* __restrict__ WpT) {
  __shared__ float tile[64][65];
  int bj = blockIdx.x, bk = blockIdx.y;  // grid (16, 8)
  int tx = threadIdx.x & 63, ty = threadIdx.x >> 6;
#pragma unroll
  for (int i = 0; i < 16; i++) {
    int r = ty + 4 * i;  // local k
    tile[r][tx] = Wp[(size_t)(bk * 64 + r) * DIM + bj * 64 + tx];
  }
  __syncthreads();
#pragma unroll
  for (int i = 0; i < 16; i++) {
    int r = ty + 4 * i;  // local j
    WpT[(size_t)(bj * 64 + r) * 512 + bk * 64 + tx] = __float2bfloat16(tile[tx][r]);
  }
}

// --- Kernel 2b: build B-fragment tables for W2 and An (bf16) -------------
// W2B[((k*4+nt)*4+ks)*512 + lane*8 + j] = W2[k][e=ks*32+(lane>>4)*8+j][n=nt*16+(lane&15)]
// AnB[ks*512 + lane*8 + j]             = An[a=lane&15][e=ks*32+(lane>>4)*8+j]
__global__ __launch_bounds__(256) void kprep(
    const float* __restrict__ W2, const float* __restrict__ An,
    __hip_bfloat16* __restrict__ W2B, __hip_bfloat16* __restrict__ AnB) {
  int id = blockIdx.x * 256 + threadIdx.x;
  if (id < 65536) {
    int j = id & 7, lane = (id >> 3) & 63, ks = (id >> 9) & 3,
        nt = (id >> 11) & 3, k = id >> 13;
    int e = ks * 32 + (lane >> 4) * 8 + j;
    int n = nt * 16 + (lane & 15);
    W2B[id] = __float2bfloat16(W2[k * (DC2 * DC) + e * DC + n]);
  } else {
    int id2 = id - 65536;  // 16384 elems
    int j = id2 & 7, lane = (id2 >> 3) & 63, ks = id2 >> 9;  // ks in [0,32)
    int e = ks * 32 + (lane >> 4) * 8 + j;
    int a = lane & 15;
    AnB[id2] = __float2bfloat16(An[a * DIM + e]);
  }
}

// ---------------- Kernel 3: 8 tokens/block -> y (N x 512 bf16) ----------
// DS-op diet vs previous version (~230 -> ~90 DS ops/wave):
//  - Phase A/D reductions via DPP row_ror adds (VALU pipe, 0 DS)
//  - Phase C: thread owns 4 consecutive elems of one comp -> 2 broadcast
//    tri reads + 1 ds_write_b64 per token (was 8 reads + 4 b16 writes)
//  - part[] halved to 2 KB (only rows m<8 stored)
#define LDA_H 1032  // 1024 + 8 bf16 pad: row stride 2064 B = 516 dw, 516%32=4
__global__ __launch_bounds__(256, 7) void ktoken(
    const float* __restrict__ x, const __hip_bfloat16* __restrict__ AnB,
    const float* __restrict__ ln_g, const float* __restrict__ ln_b,
    const float* __restrict__ W1, const float* __restrict__ b1,
    const __hip_bfloat16* __restrict__ W2B, const float* __restrict__ b2,
    const float* __restrict__ cg, const float* __restrict__ cb,
    __hip_bfloat16* __restrict__ yout) {
  int t = threadIdx.x;
  int lane = t & 63, w = t >> 6;
  int l15 = lane & 15, quad = lane >> 4;
  int n0 = blockIdx.x * 8;

  __shared__ __hip_bfloat16 hu[8 * LDA_H];  // 16.1 KB: h, then u
  __shared__ float tri_s[8 * 16];           // [token][anchor]  512 B
  __shared__ float part[4 * 32 * 4];        // tri partials, rows m<8 only, 2 KB

  // ---- Phase A: LN + l2norm for tokens w*2, w*2+1 (one wave each) ----
  // element mapping: lane holds elements i*256 + lane*4 + j (float4 loads)
  float gv[16], bv[16];
#pragma unroll
  for (int i = 0; i < 4; i++) {
    f32x4 g4 = *(const f32x4*)(&ln_g[i * 256 + lane * 4]);
    f32x4 b4 = *(const f32x4*)(&ln_b[i * 256 + lane * 4]);
#pragma unroll
    for (int j = 0; j < 4; j++) { gv[i * 4 + j] = g4[j]; bv[i * 4 + j] = b4[j]; }
  }
#pragma unroll
  for (int it = 0; it < 2; it++) {
    int tok = w * 2 + it;
    const float* xr = x + (size_t)(n0 + tok) * DIM;
    float xv[16], s = 0.f, s2 = 0.f;
#pragma unroll
    for (int i = 0; i < 4; i++) {
      f32x4 v4 = *(const f32x4*)(&xr[i * 256 + lane * 4]);
#pragma unroll
      for (int j = 0; j < 4; j++) {
        float v = v4[j];
        xv[i * 4 + j] = v; s += v; s2 += v * v;
      }
    }
    s = wavesum64(s);
    s2 = wavesum64(s2);
    float mu = s * (1.f / DIM);
    float rstd = rsqrtf(s2 * (1.f / DIM) - mu * mu + EPS_LN);
    float ss = 0.f;
#pragma unroll
    for (int i = 0; i < 16; i++) {
      float h = (xv[i] - mu) * rstd * gv[i] + bv[i];
      xv[i] = h; ss += h * h;
    }
    ss = wavesum64(ss);
    float inv = 1.f / fmaxf(sqrtf(ss), EPS_NORM);
#pragma unroll
    for (int i = 0; i < 4; i++) {
      union { uint2 u; __hip_bfloat16 h[4]; } pk;
#pragma unroll
      for (int j = 0; j < 4; j++) pk.h[j] = __float2bfloat16(xv[i * 4 + j] * inv);
      *(uint2*)(&hu[tok * LDA_H + i * 256 + lane * 4]) = pk.u;
    }
  }
  __syncthreads();

  // ---- Phase B: tri[m][a] = 1 - sum_e h[m][e]*An[a][e], MFMA over K=1024 ----
  {
    f32x4 tacc = {0.f, 0.f, 0.f, 0.f};
    int ar = l15 & 7;  // clamp A rows: tokens 8-15 duplicate 0-7, outputs unused
#pragma unroll
    for (int ks = w * 8; ks < w * 8 + 8; ks++) {
      bf16x8 afr = *(const bf16x8*)(&hu[ar * LDA_H + ks * 32 + quad * 8]);
      bf16x8 bfr = *(const bf16x8*)(&AnB[ks * 512 + lane * 8]);
      tacc = __builtin_amdgcn_mfma_f32_16x16x32_bf16(afr, bfr, tacc, 0, 0, 0);
    }
    if (quad < 2) *(f32x4*)(&part[(w * 32 + (lane & 31)) * 4]) = tacc;
  }
  __syncthreads();
  if (t < 128) {
    int ln = t & 31, rg = t >> 5;
    float v = part[(0 * 32 + ln) * 4 + rg] + part[(1 * 32 + ln) * 4 + rg] +
              part[(2 * 32 + ln) * 4 + rg] + part[(3 * 32 + ln) * 4 + rg];
    int m = (ln >> 4) * 4 + rg, a = ln & 15;  // m in [0,8)
    tri_s[m * 16 + a] = 1.f - v;
  }
  __syncthreads();

  // ---- Phase C: u = relu(tri0*W1a + tri1*W1b + b1)^2 -> hu (bf16) ----
  // thread t owns elements 4t..4t+3 (comp k = t>>5, within-comp e0 = (4t)&127)
  {
    int k = t >> 5;
    int e0 = (t * 4) & 127;
    f32x4 w1a = *(const f32x4*)(&W1[k * 256 + e0]);
    f32x4 w1b = *(const f32x4*)(&W1[k * 256 + 128 + e0]);
    f32x4 b1v = *(const f32x4*)(&b1[k * 128 + e0]);
#pragma unroll
    for (int tok = 0; tok < 8; tok++) {
      float t0 = tri_s[tok * 16 + k], t1 = tri_s[tok * 16 + 8 + k];
      union { unsigned long long u; __hip_bfloat16 h[4]; } pk;
#pragma unroll
      for (int j = 0; j < 4; j++) {
        float uu = t0 * w1a[j] + t1 * w1b[j] + b1v[j];
        uu = fmaxf(uu, 0.f);
        pk.h[j] = __float2bfloat16(uu * uu);
      }
      *(unsigned long long*)(&hu[tok * LDA_H + t * 4]) = pk.u;
    }
  }
  __syncthreads();

  // ---- Phase D: per-comp y = u@W2 + b2, LN over dc=64, write ----
  // wave w handles comps 2w, 2w+1
#pragma unroll
  for (int kc = 0; kc < 2; kc++) {
    int k = w * 2 + kc;
    int ar = l15 & 7;
    bf16x8 afr[4];
#pragma unroll
    for (int ks = 0; ks < 4; ks++)
      afr[ks] = *(const bf16x8*)(&hu[ar * LDA_H + k * 128 + ks * 32 + quad * 8]);
    f32x4 acc[4] = {{0,0,0,0},{0,0,0,0},{0,0,0,0},{0,0,0,0}};
#pragma unroll
    for (int nt = 0; nt < 4; nt++) {
#pragma unroll
      for (int ks = 0; ks < 4; ks++) {
        bf16x8 bfr = *(const bf16x8*)(&W2B[(size_t)(((k * 4 + nt) * 4 + ks)) * 512 + lane * 8]);
        acc[nt] = __builtin_amdgcn_mfma_f32_16x16x32_bf16(afr[ks], bfr, acc[nt], 0, 0, 0);
      }
    }
    // add b2, LN over 64 (token m = quad*4+reg; its 64 vals live in this quad)
    float vals[4][4], s1[4] = {0,0,0,0}, s2[4] = {0,0,0,0};
#pragma unroll
    for (int nt = 0; nt < 4; nt++) {
      float b2v = b2[k * 64 + nt * 16 + l15];
#pragma unroll
      for (int r = 0; r < 4; r++) {
        float v = acc[nt][r] + b2v;
        vals[nt][r] = v; s1[r] += v; s2[r] += v * v;
      }
    }
#pragma unroll
    for (int r = 0; r < 4; r++) {
      s1[r] = rowsum16(s1[r]);  // DPP, 0 DS ops
      s2[r] = rowsum16(s2[r]);
    }
#pragma unroll
    for (int r = 0; r < 4; r++) {
      float mu = s1[r] * (1.f / DC);
      float rs = rsqrtf(s2[r] * (1.f / DC) - mu * mu + EPS_LN);
      int tokrow = quad * 4 + r;
      if (tokrow < 8) {
#pragma unroll
        for (int nt = 0; nt < 4; nt++) {
          int d = nt * 16 + l15;
          float yn = (vals[nt][r] - mu) * rs * cg[k * 64 + d] + cb[k * 64 + d];
          yout[(size_t)(n0 + tokrow) * 512 + k * 64 + d] = __float2bfloat16(yn);
        }
      }
    }
  }
}

// ---------------- Kernel 4: out = x + sig(gate)*(y @ Wp + bp) -----------
#define LDP 72
__global__ __launch_bounds__(256) void kgemm(
    const __hip_bfloat16* __restrict__ Y, const __hip_bfloat16* __restrict__ WpT,
    const float* __restrict__ x, const float* __restrict__ bp,
    const float* __restrict__ gate, float* __restrict__ out) {
  __shared__ alignas(16) __hip_bfloat16 As[128 * LDP];
  __shared__ alignas(16) __hip_bfloat16 Bs[128 * LDP];
  int t = threadIdx.x, lane = t & 63, wid = t >> 6;
  int bm = blockIdx.x, bj = blockIdx.y;
  int wm = (wid >> 1) * 64, wj = (wid & 1) * 64;
  int l15 = lane & 15, quad = lane >> 4;

  f32x4 acc[4][4] = {};

  for (int k0 = 0; k0 < 512; k0 += 64) {
#pragma unroll
    for (int it = 0; it < 4; it++) {
      int c = it * 256 + t;
      int row = c >> 3, col = (c & 7) * 8;
      *(uint4*)(&As[row * LDP + col]) =
          *(const uint4*)(&Y[(size_t)(bm * 128 + row) * 512 + k0 + col]);
      *(uint4*)(&Bs[row * LDP + col]) =
          *(const uint4*)(&WpT[(size_t)(bj * 128 + row) * 512 + k0 + col]);
    }
    __syncthreads();
#pragma unroll
    for (int kk = 0; kk < 64; kk += 32) {
      bf16x8 af[4], bfr[4];
#pragma unroll
      for (int i = 0; i < 4; i++) {
        af[i]  = *(const bf16x8*)(&As[(wm + i * 16 + l15) * LDP + kk + quad * 8]);
        bfr[i] = *(const bf16x8*)(&Bs[(wj + i * 16 + l15) * LDP + kk + quad * 8]);
      }
#pragma unroll
      for (int i = 0; i < 4; i++)
#pragma unroll
        for (int j = 0; j < 4; j++)
          acc[i][j] = __builtin_amdgcn_mfma_f32_16x16x32_bf16(af[i], bfr[j], acc[i][j], 0, 0, 0);
    }
    __syncthreads();
  }

  float sg[4], bpv[4];
#pragma unroll
  for (int j = 0; j < 4; j++) {
    int gc = bj * 128 + wj + j * 16 + l15;
    sg[j] = 1.f / (1.f + expf(-gate[gc]));
    bpv[j] = bp[gc];
  }
#pragma unroll
  for (int i = 0; i < 4; i++) {
#pragma unroll
    for (int j = 0; j < 4; j++) {
      int gc = bj * 128 + wj + j * 16 + l15;
#pragma unroll
      for (int r = 0; r < 4; r++) {
        int gr = bm * 128 + wm + i * 16 + quad * 4 + r;   // D row=(lane>>4)*4+reg
        size_t idx = (size_t)gr * DIM + gc;
        out[idx] = x[idx] + sg[j] * (acc[i][j][r] + bpv[j]);
      }
    }
  }
}

extern "C" void kernel_launch(void* const* d_in, const int* in_sizes, int n_in,
                              void* d_out, int out_size, void* d_ws, size_t ws_size,
                              hipStream_t stream) {
  const float* x       = (const float*)d_in[0];
  const float* anchors = (const float*)d_in[1];
  const float* ln_g    = (const float*)d_in[2];
  const float* ln_b    = (const float*)d_in[3];
  const float* W1      = (const float*)d_in[4];
  const float* b1      = (const float*)d_in[5];
  const float* W2      = (const float*)d_in[6];
  const float* b2      = (const float*)d_in[7];
  const float* cg      = (const float*)d_in[8];
  const float* cb      = (const float*)d_in[9];
  const float* Wp      = (const float*)d_in[10];
  const float* bp      = (const float*)d_in[11];
  const float* gate    = (const float*)d_in[12];

  int N = in_sizes[0] / DIM;  // 32768 tokens

  char* w = (char*)d_ws;
  size_t off = 0;
  float* An           = (float*)(w + off);           off += 64 << 10;   // 64 KB
  __hip_bfloat16* WpT = (__hip_bfloat16*)(w + off);  off += 1 << 20;    // 1 MB
  __hip_bfloat16* W2B = (__hip_bfloat16*)(w + off);  off += 128 << 10;  // 128 KB
  __hip_bfloat16* AnB = (__hip_bfloat16*)(w + off);  off += 32 << 10;   // 32 KB
  __hip_bfloat16* Yb  = (__hip_bfloat16*)(w + off);                     // N*512*2 = 32 MB

  knorm_anchors<<<NANCH, 256, 0, stream>>>(anchors, An);
  ktrans<<<dim3(16, 8), 256, 0, stream>>>(Wp, WpT);
  kprep<<<320, 256, 0, stream>>>(W2, An, W2B, AnB);
  ktoken<<<N / 8, 256, 0, stream>>>(x, AnB, ln_g, ln_b, W1, b1, W2B, b2, cg, cb, Yb);
  kgemm<<<dim3(N / 128, DIM / 128), 256, 0, stream>>>(Yb, WpT, x, bp, gate,
                                                      (float*)d_out);
}

// Round 3
// 342.066 us; speedup vs baseline: 1.0534x; 1.0377x over previous
//
#include <hip/hip_runtime.h>
#include <hip/hip_bf16.h>

// Problem constants (B=8,S=4096,D=1024, A=16, C=8, dc=64, apc=2)
#define DIM 1024
#define NANCH 16
#define NCOMP 8
#define DC 64
#define DC2 128
#define EPS_LN 1e-5f
#define EPS_NORM 1e-12f

typedef __bf16 bf16x8 __attribute__((ext_vector_type(8)));
typedef float f32x4 __attribute__((ext_vector_type(4)));

// ---- DPP rotate-reduce helpers: sum over 16-lane row, result in all lanes.
template <int CTRL>
__device__ __forceinline__ float rr_add(float v) {
  return v + __int_as_float(__builtin_amdgcn_update_dpp(
                 0, __float_as_int(v), CTRL, 0xF, 0xF, true));
}
__device__ __forceinline__ float rowsum16(float v) {
  v = rr_add<0x121>(v);  // row_ror:1
  v = rr_add<0x122>(v);  // row_ror:2
  v = rr_add<0x124>(v);  // row_ror:4
  v = rr_add<0x128>(v);  // row_ror:8
  return v;
}
__device__ __forceinline__ float wavesum64(float v) {
  v = rowsum16(v);
  v += __shfl_xor(v, 16);
  v += __shfl_xor(v, 32);
  return v;
}

// async global->LDS, 16 B per lane (dest must be wave-uniform base + lane*16)
__device__ __forceinline__ void gload16(const __hip_bfloat16* g, __hip_bfloat16* l) {
  __builtin_amdgcn_global_load_lds(
      (const __attribute__((address_space(1))) unsigned int*)g,
      (__attribute__((address_space(3))) unsigned int*)l, 16, 0, 0);
}

// ---------------- Kernel 1: normalize anchors -> f32 ----------------
__global__ __launch_bounds__(256) void knorm_anchors(
    const float* __restrict__ anchors, float* __restrict__ An) {
  int a = blockIdx.x, t = threadIdx.x;
  int lane = t & 63, wid = t >> 6;
  __shared__ float red[4];
  float v[4]; float ss = 0.f;
#pragma unroll
  for (int i = 0; i < 4; i++) {
    v[i] = anchors[a * DIM + t + 256 * i];
    ss += v[i] * v[i];
  }
  for (int off = 32; off; off >>= 1) ss += __shfl_down(ss, off);
  if (lane == 0) red[wid] = ss;
  __syncthreads();
  float inv = 1.f / fmaxf(sqrtf(red[0] + red[1] + red[2] + red[3]), EPS_NORM);
#pragma unroll
  for (int i = 0; i < 4; i++) An[a * DIM + t + 256 * i] = v[i] * inv;
}

// ------- Kernel 2: transpose Wp (512x1024 f32) -> WpT (1024x512 bf16) ----
__global__ __launch_bounds__(256) void ktrans(
    const float* __restrict__ Wp, __hip_bfloat16* __restrict__ WpT) {
  __shared__ float tile[64][65];
  int bj = blockIdx.x, bk = blockIdx.y;  // grid (16, 8)
  int tx = threadIdx.x & 63, ty = threadIdx.x >> 6;
#pragma unroll
  for (int i = 0; i < 16; i++) {
    int r = ty + 4 * i;  // local k
    tile[r][tx] = Wp[(size_t)(bk * 64 + r) * DIM + bj * 64 + tx];
  }
  __syncthreads();
#pragma unroll
  for (int i = 0; i < 16; i++) {
    int r = ty + 4 * i;  // local j
    WpT[(size_t)(bj * 64 + r) * 512 + bk * 64 + tx] = __float2bfloat16(tile[tx][r]);
  }
}

// --- Kernel 2b: build B-fragment tables for W2 and An (bf16) -------------
__global__ __launch_bounds__(256) void kprep(
    const float* __restrict__ W2, const float* __restrict__ An,
    __hip_bfloat16* __restrict__ W2B, __hip_bfloat16* __restrict__ AnB) {
  int id = blockIdx.x * 256 + threadIdx.x;
  if (id < 65536) {
    int j = id & 7, lane = (id >> 3) & 63, ks = (id >> 9) & 3,
        nt = (id >> 11) & 3, k = id >> 13;
    int e = ks * 32 + (lane >> 4) * 8 + j;
    int n = nt * 16 + (lane & 15);
    W2B[id] = __float2bfloat16(W2[k * (DC2 * DC) + e * DC + n]);
  } else {
    int id2 = id - 65536;  // 16384 elems
    int j = id2 & 7, lane = (id2 >> 3) & 63, ks = id2 >> 9;  // ks in [0,32)
    int e = ks * 32 + (lane >> 4) * 8 + j;
    int a = lane & 15;
    AnB[id2] = __float2bfloat16(An[a * DIM + e]);
  }
}

// ---------------- Kernel 3: 8 tokens/block -> y (N x 512 bf16) ----------
// Round-3 change: ALL global MFMA B-fragments are prefetched into VGPRs
// far ahead of use (AnB before Phase A; W2B comp-0 before Phase C, comp-1
// under comp-0's epilogue). launch_bounds(256,4) gives the allocator room
// (rounds 0-1 proved occupancy is not the limiter here).
#define LDA_H 1032  // 1024 + 8 bf16 pad
__global__ __launch_bounds__(256, 4) void ktoken(
    const float* __restrict__ x, const __hip_bfloat16* __restrict__ AnB,
    const float* __restrict__ ln_g, const float* __restrict__ ln_b,
    const float* __restrict__ W1, const float* __restrict__ b1,
    const __hip_bfloat16* __restrict__ W2B, const float* __restrict__ b2,
    const float* __restrict__ cg, const float* __restrict__ cb,
    __hip_bfloat16* __restrict__ yout) {
  int t = threadIdx.x;
  int lane = t & 63, w = t >> 6;
  int l15 = lane & 15, quad = lane >> 4;
  int n0 = blockIdx.x * 8;

  __shared__ __hip_bfloat16 hu[8 * LDA_H];  // 16.1 KB: h, then u
  __shared__ float tri_s[8 * 16];
  __shared__ float part[4 * 32 * 4];

  // ---- prefetch Phase-B AnB fragments NOW; consumed ~3K cycles later ----
  bf16x8 anb[8];
#pragma unroll
  for (int i = 0; i < 8; i++)
    anb[i] = *(const bf16x8*)(&AnB[(w * 8 + i) * 512 + lane * 8]);

  // ---- Phase A: LN + l2norm for tokens w*2, w*2+1 (one wave each) ----
  float gv[16], bv[16];
#pragma unroll
  for (int i = 0; i < 4; i++) {
    f32x4 g4 = *(const f32x4*)(&ln_g[i * 256 + lane * 4]);
    f32x4 b4 = *(const f32x4*)(&ln_b[i * 256 + lane * 4]);
#pragma unroll
    for (int j = 0; j < 4; j++) { gv[i * 4 + j] = g4[j]; bv[i * 4 + j] = b4[j]; }
  }
  // issue BOTH tokens' x loads before any reduction (one latency wait, not two)
  f32x4 xv4[2][4];
#pragma unroll
  for (int it = 0; it < 2; it++) {
    const float* xr = x + (size_t)(n0 + w * 2 + it) * DIM;
#pragma unroll
    for (int i = 0; i < 4; i++)
      xv4[it][i] = *(const f32x4*)(&xr[i * 256 + lane * 4]);
  }
#pragma unroll
  for (int it = 0; it < 2; it++) {
    int tok = w * 2 + it;
    float xv[16], s = 0.f, s2 = 0.f;
#pragma unroll
    for (int i = 0; i < 4; i++) {
#pragma unroll
      for (int j = 0; j < 4; j++) {
        float v = xv4[it][i][j];
        xv[i * 4 + j] = v; s += v; s2 += v * v;
      }
    }
    s = wavesum64(s);
    s2 = wavesum64(s2);
    float mu = s * (1.f / DIM);
    float rstd = rsqrtf(s2 * (1.f / DIM) - mu * mu + EPS_LN);
    float ss = 0.f;
#pragma unroll
    for (int i = 0; i < 16; i++) {
      float h = (xv[i] - mu) * rstd * gv[i] + bv[i];
      xv[i] = h; ss += h * h;
    }
    ss = wavesum64(ss);
    float inv = 1.f / fmaxf(sqrtf(ss), EPS_NORM);
#pragma unroll
    for (int i = 0; i < 4; i++) {
      union { uint2 u; __hip_bfloat16 h[4]; } pk;
#pragma unroll
      for (int j = 0; j < 4; j++) pk.h[j] = __float2bfloat16(xv[i * 4 + j] * inv);
      *(uint2*)(&hu[tok * LDA_H + i * 256 + lane * 4]) = pk.u;
    }
  }
  __syncthreads();

  // ---- Phase B: tri[m][a] = 1 - h@An^T, MFMA over K=1024 (anb in regs) ----
  {
    f32x4 tacc = {0.f, 0.f, 0.f, 0.f};
    int ar = l15 & 7;
#pragma unroll
    for (int i = 0; i < 8; i++) {
      int ks = w * 8 + i;
      bf16x8 afr = *(const bf16x8*)(&hu[ar * LDA_H + ks * 32 + quad * 8]);
      tacc = __builtin_amdgcn_mfma_f32_16x16x32_bf16(afr, anb[i], tacc, 0, 0, 0);
    }
    if (quad < 2) *(f32x4*)(&part[(w * 32 + (lane & 31)) * 4]) = tacc;
  }
  __syncthreads();
  if (t < 128) {
    int ln = t & 31, rg = t >> 5;
    float v = part[(0 * 32 + ln) * 4 + rg] + part[(1 * 32 + ln) * 4 + rg] +
              part[(2 * 32 + ln) * 4 + rg] + part[(3 * 32 + ln) * 4 + rg];
    int m = (ln >> 4) * 4 + rg, a = ln & 15;  // m in [0,8)
    tri_s[m * 16 + a] = 1.f - v;
  }

  // ---- prefetch Phase-D comp (w*2) B-fragments; consumed after Phase C ----
  bf16x8 bfv[16];
#pragma unroll
  for (int q = 0; q < 16; q++)
    bfv[q] = *(const bf16x8*)(&W2B[(size_t)((w * 2) * 16 + q) * 512 + lane * 8]);
  __syncthreads();

  // ---- Phase C: u = relu(tri0*W1a + tri1*W1b + b1)^2 -> hu (bf16) ----
  {
    int k = t >> 5;
    int e0 = (t * 4) & 127;
    f32x4 w1a = *(const f32x4*)(&W1[k * 256 + e0]);
    f32x4 w1b = *(const f32x4*)(&W1[k * 256 + 128 + e0]);
    f32x4 b1v = *(const f32x4*)(&b1[k * 128 + e0]);
#pragma unroll
    for (int tok = 0; tok < 8; tok++) {
      float t0 = tri_s[tok * 16 + k], t1 = tri_s[tok * 16 + 8 + k];
      union { unsigned long long u; __hip_bfloat16 h[4]; } pk;
#pragma unroll
      for (int j = 0; j < 4; j++) {
        float uu = t0 * w1a[j] + t1 * w1b[j] + b1v[j];
        uu = fmaxf(uu, 0.f);
        pk.h[j] = __float2bfloat16(uu * uu);
      }
      *(unsigned long long*)(&hu[tok * LDA_H + t * 4]) = pk.u;
    }
  }
  __syncthreads();

  // ---- Phase D: per-comp y = u@W2 + b2, LN over dc=64, write ----
#pragma unroll
  for (int kc = 0; kc < 2; kc++) {
    int k = w * 2 + kc;
    int ar = l15 & 7;
    bf16x8 afr[4];
#pragma unroll
    for (int ks = 0; ks < 4; ks++)
      afr[ks] = *(const bf16x8*)(&hu[ar * LDA_H + k * 128 + ks * 32 + quad * 8]);
    f32x4 acc[4] = {{0,0,0,0},{0,0,0,0},{0,0,0,0},{0,0,0,0}};
#pragma unroll
    for (int nt = 0; nt < 4; nt++) {
#pragma unroll
      for (int ks = 0; ks < 4; ks++)
        acc[nt] = __builtin_amdgcn_mfma_f32_16x16x32_bf16(afr[ks], bfv[nt * 4 + ks],
                                                          acc[nt], 0, 0, 0);
    }
    if (kc == 0) {
      // prefetch comp w*2+1 fragments under comp-0's LN epilogue
#pragma unroll
      for (int q = 0; q < 16; q++)
        bfv[q] = *(const bf16x8*)(&W2B[(size_t)((w * 2 + 1) * 16 + q) * 512 + lane * 8]);
    }
    // add b2, LN over 64 (token m = quad*4+reg; its 64 vals live in this quad)
    float vals[4][4], s1[4] = {0,0,0,0}, s2[4] = {0,0,0,0};
#pragma unroll
    for (int nt = 0; nt < 4; nt++) {
      float b2v = b2[k * 64 + nt * 16 + l15];
#pragma unroll
      for (int r = 0; r < 4; r++) {
        float v = acc[nt][r] + b2v;
        vals[nt][r] = v; s1[r] += v; s2[r] += v * v;
      }
    }
#pragma unroll
    for (int r = 0; r < 4; r++) {
      s1[r] = rowsum16(s1[r]);
      s2[r] = rowsum16(s2[r]);
    }
#pragma unroll
    for (int r = 0; r < 4; r++) {
      float mu = s1[r] * (1.f / DC);
      float rs = rsqrtf(s2[r] * (1.f / DC) - mu * mu + EPS_LN);
      int tokrow = quad * 4 + r;
      if (tokrow < 8) {
#pragma unroll
        for (int nt = 0; nt < 4; nt++) {
          int d = nt * 16 + l15;
          float yn = (vals[nt][r] - mu) * rs * cg[k * 64 + d] + cb[k * 64 + d];
          yout[(size_t)(n0 + tokrow) * 512 + k * 64 + d] = __float2bfloat16(yn);
        }
      }
    }
  }
}

// ---------------- Kernel 4: out = x + sig(gate)*(y @ Wp + bp) -----------
// m97 structure: global_load_lds 16B staging into LINEAR LDS with
// both-sides XOR swizzle (pre-swizzled global source column + swizzled
// ds_read). Row pitch 128 B; read swizzle byte ^= (row&7)<<4 -> 2-way
// bank aliasing (free). 32 KB LDS -> 5 blocks/CU.
__global__ __launch_bounds__(256, 4) void kgemm(
    const __hip_bfloat16* __restrict__ Y, const __hip_bfloat16* __restrict__ WpT,
    const float* __restrict__ x, const float* __restrict__ bp,
    const float* __restrict__ gate, float* __restrict__ out) {
  __shared__ alignas(16) __hip_bfloat16 As[128 * 64];  // 16 KB, swizzled content
  __shared__ alignas(16) __hip_bfloat16 Bs[128 * 64];  // 16 KB
  int t = threadIdx.x, lane = t & 63, wid = t >> 6;
  int bm = blockIdx.x, bj = blockIdx.y;
  int wm = (wid >> 1) * 64, wj = (wid & 1) * 64;
  int l15 = lane & 15, quad = lane >> 4;

  f32x4 acc[4][4] = {};

  // staging geometry: issue 'it' covers LDS bytes [it*4096 + t*16, +16)
  // dest row = it*32 + t/8, dest col-byte = (t%8)*16  (linear)
  // source col-byte pre-swizzled: csw = colb ^ ((row&7)<<4)
  int srow[4], scol[4];
#pragma unroll
  for (int it = 0; it < 4; it++) {
    int byteo = it * 4096 + t * 16;
    int row = byteo >> 7, colb = byteo & 127;
    srow[it] = row;
    scol[it] = (colb ^ ((row & 7) << 4)) >> 1;  // element index in [0,64)
  }

  for (int kt = 0; kt < 8; kt++) {
    int k0 = kt * 64;
#pragma unroll
    for (int it = 0; it < 4; it++) {
      gload16(Y + (size_t)(bm * 128 + srow[it]) * 512 + k0 + scol[it],
              As + (it * 4096 + t * 16) / 2);
      gload16(WpT + (size_t)(bj * 128 + srow[it]) * 512 + k0 + scol[it],
              Bs + (it * 4096 + t * 16) / 2);
    }
    __syncthreads();  // drains vmcnt -> tiles ready
#pragma unroll
    for (int kk = 0; kk < 64; kk += 32) {
      bf16x8 af[4], bfr[4];
#pragma unroll
      for (int i = 0; i < 4; i++) {
        int ra = wm + i * 16 + l15, rb = wj + i * 16 + l15;
        int cb2 = (kk + quad * 8) * 2;
        af[i]  = *(const bf16x8*)((const char*)As + ra * 128 + (cb2 ^ ((ra & 7) << 4)));
        bfr[i] = *(const bf16x8*)((const char*)Bs + rb * 128 + (cb2 ^ ((rb & 7) << 4)));
      }
#pragma unroll
      for (int i = 0; i < 4; i++)
#pragma unroll
        for (int j = 0; j < 4; j++)
          acc[i][j] = __builtin_amdgcn_mfma_f32_16x16x32_bf16(af[i], bfr[j], acc[i][j], 0, 0, 0);
    }
    __syncthreads();
  }

  float sg[4], bpv[4];
#pragma unroll
  for (int j = 0; j < 4; j++) {
    int gc = bj * 128 + wj + j * 16 + l15;
    sg[j] = 1.f / (1.f + expf(-gate[gc]));
    bpv[j] = bp[gc];
  }
#pragma unroll
  for (int i = 0; i < 4; i++) {
#pragma unroll
    for (int j = 0; j < 4; j++) {
      int gc = bj * 128 + wj + j * 16 + l15;
#pragma unroll
      for (int r = 0; r < 4; r++) {
        int gr = bm * 128 + wm + i * 16 + quad * 4 + r;
        size_t idx = (size_t)gr * DIM + gc;
        out[idx] = x[idx] + sg[j] * (acc[i][j][r] + bpv[j]);
      }
    }
  }
}

extern "C" void kernel_launch(void* const* d_in, const int* in_sizes, int n_in,
                              void* d_out, int out_size, void* d_ws, size_t ws_size,
                              hipStream_t stream) {
  const float* x       = (const float*)d_in[0];
  const float* anchors = (const float*)d_in[1];
  const float* ln_g    = (const float*)d_in[2];
  const float* ln_b    = (const float*)d_in[3];
  const float* W1      = (const float*)d_in[4];
  const float* b1      = (const float*)d_in[5];
  const float* W2      = (const float*)d_in[6];
  const float* b2      = (const float*)d_in[7];
  const float* cg      = (const float*)d_in[8];
  const float* cb      = (const float*)d_in[9];
  const float* Wp      = (const float*)d_in[10];
  const float* bp      = (const float*)d_in[11];
  const float* gate    = (const float*)d_in[12];

  int N = in_sizes[0] / DIM;  // 32768 tokens

  char* w = (char*)d_ws;
  size_t off = 0;
  float* An           = (float*)(w + off);           off += 64 << 10;   // 64 KB
  __hip_bfloat16* WpT = (__hip_bfloat16*)(w + off);  off += 1 << 20;    // 1 MB
  __hip_bfloat16* W2B = (__hip_bfloat16*)(w + off);  off += 128 << 10;  // 128 KB
  __hip_bfloat16* AnB = (__hip_bfloat16*)(w + off);  off += 32 << 10;   // 32 KB
  __hip_bfloat16* Yb  = (__hip_bfloat16*)(w + off);                     // 32 MB

  knorm_anchors<<<NANCH, 256, 0, stream>>>(anchors, An);
  ktrans<<<dim3(16, 8), 256, 0, stream>>>(Wp, WpT);
  kprep<<<320, 256, 0, stream>>>(W2, An, W2B, AnB);
  ktoken<<<N / 8, 256, 0, stream>>>(x, AnB, ln_g, ln_b, W1, b1, W2B, b2, cg, cb, Yb);
  kgemm<<<dim3(N / 128, DIM / 128), 256, 0, stream>>>(Yb, WpT, x, bp, gate,
                                                      (float*)d_out);
}

// Round 5
// 340.915 us; speedup vs baseline: 1.0569x; 1.0034x over previous
//
#include <hip/hip_runtime.h>
#include <hip/hip_bf16.h>

// Problem constants (B=8,S=4096,D=1024, A=16, C=8, dc=64, apc=2)
#define DIM 1024
#define NANCH 16
#define NCOMP 8
#define DC 64
#define DC2 128
#define EPS_LN 1e-5f
#define EPS_NORM 1e-12f

typedef __bf16 bf16x8 __attribute__((ext_vector_type(8)));
typedef float f32x4 __attribute__((ext_vector_type(4)));

// ---- DPP rotate-reduce helpers: sum over 16-lane row, result in all lanes.
template <int CTRL>
__device__ __forceinline__ float rr_add(float v) {
  return v + __int_as_float(__builtin_amdgcn_update_dpp(
                 0, __float_as_int(v), CTRL, 0xF, 0xF, true));
}
__device__ __forceinline__ float rowsum16(float v) {
  v = rr_add<0x121>(v);  // row_ror:1
  v = rr_add<0x122>(v);  // row_ror:2
  v = rr_add<0x124>(v);  // row_ror:4
  v = rr_add<0x128>(v);  // row_ror:8
  return v;
}
__device__ __forceinline__ float wavesum64(float v) {
  v = rowsum16(v);
  v += __shfl_xor(v, 16);
  v += __shfl_xor(v, 32);
  return v;
}

// async global->LDS, 16 B per lane (dest must be wave-uniform base + lane*16)
__device__ __forceinline__ void gload16(const __hip_bfloat16* g, __hip_bfloat16* l) {
  __builtin_amdgcn_global_load_lds(
      (const __attribute__((address_space(1))) unsigned int*)g,
      (__attribute__((address_space(3))) unsigned int*)l, 16, 0, 0);
}

// ---------------- Kernel P: fused prep (one launch instead of three) ----
// blocks [0,16):    normalize anchor row a=b, emit AnB fragments directly
// blocks [16,144):  transpose Wp (512x1024 f32) -> WpT (1024x512 bf16)
// blocks [144,400): build W2B fragment table
__global__ __launch_bounds__(256) void kprepall(
    const float* __restrict__ anchors, const float* __restrict__ Wp,
    const float* __restrict__ W2, __hip_bfloat16* __restrict__ WpT,
    __hip_bfloat16* __restrict__ W2B, __hip_bfloat16* __restrict__ AnB) {
  __shared__ float smem[64 * 65 + 16];  // reused: anchor row / transpose tile
  int b = blockIdx.x, t = threadIdx.x;

  if (b < 16) {
    // ---- anchor normalize + AnB emit ----
    int a = b, lane = t & 63, wid = t >> 6;
    float v[4]; float ss = 0.f;
#pragma unroll
    for (int i = 0; i < 4; i++) {
      v[i] = anchors[a * DIM + t + 256 * i];
      ss += v[i] * v[i];
    }
    for (int off = 32; off; off >>= 1) ss += __shfl_down(ss, off);
    if (lane == 0) smem[4160 + wid] = ss;
    __syncthreads();
    float inv = 1.f / fmaxf(sqrtf(smem[4160] + smem[4161] + smem[4162] + smem[4163]),
                            EPS_NORM);
#pragma unroll
    for (int i = 0; i < 4; i++) smem[t + 256 * i] = v[i] * inv;
    __syncthreads();
    // AnB[ks*512 + (hi*16 + a)*8 + j] = row[ks*32 + hi*8 + j]
#pragma unroll
    for (int q = 0; q < 4; q++) {
      int idx = t * 4 + q;  // 0..1023
      int ks = idx >> 5, hi = (idx >> 3) & 3, j = idx & 7;
      AnB[ks * 512 + (hi * 16 + a) * 8 + j] = __float2bfloat16(smem[idx]);
    }
  } else if (b < 144) {
    // ---- Wp transpose ----
    int bidx = b - 16, bj = bidx & 15, bk = bidx >> 4;
    int tx = t & 63, ty = t >> 6;
#pragma unroll
    for (int i = 0; i < 16; i++) {
      int r = ty + 4 * i;  // local k
      smem[r * 65 + tx] = Wp[(size_t)(bk * 64 + r) * DIM + bj * 64 + tx];
    }
    __syncthreads();
#pragma unroll
    for (int i = 0; i < 16; i++) {
      int r = ty + 4 * i;  // local j
      WpT[(size_t)(bj * 64 + r) * 512 + bk * 64 + tx] =
          __float2bfloat16(smem[tx * 65 + r]);
    }
  } else {
    // ---- W2B fragment table ----
    int id = (b - 144) * 256 + t;  // [0, 65536)
    int j = id & 7, lane = (id >> 3) & 63, ks = (id >> 9) & 3,
        nt = (id >> 11) & 3, k = id >> 13;
    int e = ks * 32 + (lane >> 4) * 8 + j;
    int n = nt * 16 + (lane & 15);
    W2B[id] = __float2bfloat16(W2[k * (DC2 * DC) + e * DC + n]);
  }
}

// ---------------- Kernel 3: 8 tokens/block -> y (N x 512 bf16) ----------
// (round-2 version — best measured: 89.9 us, VGPR 36, occ 64%)
#define LDA_H 1032  // 1024 + 8 bf16 pad
__global__ __launch_bounds__(256, 7) void ktoken(
    const float* __restrict__ x, const __hip_bfloat16* __restrict__ AnB,
    const float* __restrict__ ln_g, const float* __restrict__ ln_b,
    const float* __restrict__ W1, const float* __restrict__ b1,
    const __hip_bfloat16* __restrict__ W2B, const float* __restrict__ b2,
    const float* __restrict__ cg, const float* __restrict__ cb,
    __hip_bfloat16* __restrict__ yout) {
  int t = threadIdx.x;
  int lane = t & 63, w = t >> 6;
  int l15 = lane & 15, quad = lane >> 4;
  int n0 = blockIdx.x * 8;

  __shared__ __hip_bfloat16 hu[8 * LDA_H];  // 16.1 KB: h, then u
  __shared__ float tri_s[8 * 16];           // 512 B
  __shared__ float part[4 * 32 * 4];        // 2 KB

  // ---- Phase A: LN + l2norm for tokens w*2, w*2+1 (one wave each) ----
  float gv[16], bv[16];
#pragma unroll
  for (int i = 0; i < 4; i++) {
    f32x4 g4 = *(const f32x4*)(&ln_g[i * 256 + lane * 4]);
    f32x4 b4 = *(const f32x4*)(&ln_b[i * 256 + lane * 4]);
#pragma unroll
    for (int j = 0; j < 4; j++) { gv[i * 4 + j] = g4[j]; bv[i * 4 + j] = b4[j]; }
  }
#pragma unroll
  for (int it = 0; it < 2; it++) {
    int tok = w * 2 + it;
    const float* xr = x + (size_t)(n0 + tok) * DIM;
    float xv[16], s = 0.f, s2 = 0.f;
#pragma unroll
    for (int i = 0; i < 4; i++) {
      f32x4 v4 = *(const f32x4*)(&xr[i * 256 + lane * 4]);
#pragma unroll
      for (int j = 0; j < 4; j++) {
        float v = v4[j];
        xv[i * 4 + j] = v; s += v; s2 += v * v;
      }
    }
    s = wavesum64(s);
    s2 = wavesum64(s2);
    float mu = s * (1.f / DIM);
    float rstd = rsqrtf(s2 * (1.f / DIM) - mu * mu + EPS_LN);
    float ss = 0.f;
#pragma unroll
    for (int i = 0; i < 16; i++) {
      float h = (xv[i] - mu) * rstd * gv[i] + bv[i];
      xv[i] = h; ss += h * h;
    }
    ss = wavesum64(ss);
    float inv = 1.f / fmaxf(sqrtf(ss), EPS_NORM);
#pragma unroll
    for (int i = 0; i < 4; i++) {
      union { uint2 u; __hip_bfloat16 h[4]; } pk;
#pragma unroll
      for (int j = 0; j < 4; j++) pk.h[j] = __float2bfloat16(xv[i * 4 + j] * inv);
      *(uint2*)(&hu[tok * LDA_H + i * 256 + lane * 4]) = pk.u;
    }
  }
  __syncthreads();

  // ---- Phase B: tri[m][a] = 1 - h@An^T, MFMA over K=1024 ----
  {
    f32x4 tacc = {0.f, 0.f, 0.f, 0.f};
    int ar = l15 & 7;  // clamp A rows: tokens 8-15 duplicate 0-7, outputs unused
#pragma unroll
    for (int ks = w * 8; ks < w * 8 + 8; ks++) {
      bf16x8 afr = *(const bf16x8*)(&hu[ar * LDA_H + ks * 32 + quad * 8]);
      bf16x8 bfr = *(const bf16x8*)(&AnB[ks * 512 + lane * 8]);
      tacc = __builtin_amdgcn_mfma_f32_16x16x32_bf16(afr, bfr, tacc, 0, 0, 0);
    }
    if (quad < 2) *(f32x4*)(&part[(w * 32 + (lane & 31)) * 4]) = tacc;
  }
  __syncthreads();
  if (t < 128) {
    int ln = t & 31, rg = t >> 5;
    float v = part[(0 * 32 + ln) * 4 + rg] + part[(1 * 32 + ln) * 4 + rg] +
              part[(2 * 32 + ln) * 4 + rg] + part[(3 * 32 + ln) * 4 + rg];
    int m = (ln >> 4) * 4 + rg, a = ln & 15;  // m in [0,8)
    tri_s[m * 16 + a] = 1.f - v;
  }
  __syncthreads();

  // ---- Phase C: u = relu(tri0*W1a + tri1*W1b + b1)^2 -> hu (bf16) ----
  {
    int k = t >> 5;
    int e0 = (t * 4) & 127;
    f32x4 w1a = *(const f32x4*)(&W1[k * 256 + e0]);
    f32x4 w1b = *(const f32x4*)(&W1[k * 256 + 128 + e0]);
    f32x4 b1v = *(const f32x4*)(&b1[k * 128 + e0]);
#pragma unroll
    for (int tok = 0; tok < 8; tok++) {
      float t0 = tri_s[tok * 16 + k], t1 = tri_s[tok * 16 + 8 + k];
      union { unsigned long long u; __hip_bfloat16 h[4]; } pk;
#pragma unroll
      for (int j = 0; j < 4; j++) {
        float uu = t0 * w1a[j] + t1 * w1b[j] + b1v[j];
        uu = fmaxf(uu, 0.f);
        pk.h[j] = __float2bfloat16(uu * uu);
      }
      *(unsigned long long*)(&hu[tok * LDA_H + t * 4]) = pk.u;
    }
  }
  __syncthreads();

  // ---- Phase D: per-comp y = u@W2 + b2, LN over dc=64, write ----
#pragma unroll
  for (int kc = 0; kc < 2; kc++) {
    int k = w * 2 + kc;
    int ar = l15 & 7;
    bf16x8 afr[4];
#pragma unroll
    for (int ks = 0; ks < 4; ks++)
      afr[ks] = *(const bf16x8*)(&hu[ar * LDA_H + k * 128 + ks * 32 + quad * 8]);
    f32x4 acc[4] = {{0,0,0,0},{0,0,0,0},{0,0,0,0},{0,0,0,0}};
#pragma unroll
    for (int nt = 0; nt < 4; nt++) {
#pragma unroll
      for (int ks = 0; ks < 4; ks++) {
        bf16x8 bfr = *(const bf16x8*)(&W2B[(size_t)(((k * 4 + nt) * 4 + ks)) * 512 + lane * 8]);
        acc[nt] = __builtin_amdgcn_mfma_f32_16x16x32_bf16(afr[ks], bfr, acc[nt], 0, 0, 0);
      }
    }
    float vals[4][4], s1[4] = {0,0,0,0}, s2[4] = {0,0,0,0};
#pragma unroll
    for (int nt = 0; nt < 4; nt++) {
      float b2v = b2[k * 64 + nt * 16 + l15];
#pragma unroll
      for (int r = 0; r < 4; r++) {
        float v = acc[nt][r] + b2v;
        vals[nt][r] = v; s1[r] += v; s2[r] += v * v;
      }
    }
#pragma unroll
    for (int r = 0; r < 4; r++) {
      s1[r] = rowsum16(s1[r]);  // DPP, 0 DS ops
      s2[r] = rowsum16(s2[r]);
    }
#pragma unroll
    for (int r = 0; r < 4; r++) {
      float mu = s1[r] * (1.f / DC);
      float rs = rsqrtf(s2[r] * (1.f / DC) - mu * mu + EPS_LN);
      int tokrow = quad * 4 + r;
      if (tokrow < 8) {
#pragma unroll
        for (int nt = 0; nt < 4; nt++) {
          int d = nt * 16 + l15;
          float yn = (vals[nt][r] - mu) * rs * cg[k * 64 + d] + cb[k * 64 + d];
          yout[(size_t)(n0 + tokrow) * 512 + k * 64 + d] = __float2bfloat16(yn);
        }
      }
    }
  }
}

// ---------------- Kernel 4: out = x + sig(gate)*(y @ Wp + bp) -----------
// R3-exact single-buffered version (harness-verified): global_load_lds 16B
// staging into LINEAR LDS with both-sides XOR swizzle; __syncthreads drains
// vmcnt before compute. 32 KB LDS.
__global__ __launch_bounds__(256, 4) void kgemm(
    const __hip_bfloat16* __restrict__ Y, const __hip_bfloat16* __restrict__ WpT,
    const float* __restrict__ x, const float* __restrict__ bp,
    const float* __restrict__ gate, float* __restrict__ out) {
  __shared__ alignas(16) __hip_bfloat16 As[128 * 64];  // 16 KB, swizzled content
  __shared__ alignas(16) __hip_bfloat16 Bs[128 * 64];  // 16 KB
  int t = threadIdx.x, lane = t & 63, wid = t >> 6;
  int bm = blockIdx.x, bj = blockIdx.y;
  int wm = (wid >> 1) * 64, wj = (wid & 1) * 64;
  int l15 = lane & 15, quad = lane >> 4;

  f32x4 acc[4][4] = {};

  // staging geometry: issue 'it' covers LDS bytes [it*4096 + t*16, +16)
  // dest row = it*32 + t/8, dest col-byte = (t%8)*16  (linear)
  // source col-byte pre-swizzled: csw = colb ^ ((row&7)<<4)
  int srow[4], scol[4];
#pragma unroll
  for (int it = 0; it < 4; it++) {
    int byteo = it * 4096 + t * 16;
    int row = byteo >> 7, colb = byteo & 127;
    srow[it] = row;
    scol[it] = (colb ^ ((row & 7) << 4)) >> 1;  // element index in [0,64)
  }

  for (int kt = 0; kt < 8; kt++) {
    int k0 = kt * 64;
#pragma unroll
    for (int it = 0; it < 4; it++) {
      gload16(Y + (size_t)(bm * 128 + srow[it]) * 512 + k0 + scol[it],
              As + (it * 4096 + t * 16) / 2);
      gload16(WpT + (size_t)(bj * 128 + srow[it]) * 512 + k0 + scol[it],
              Bs + (it * 4096 + t * 16) / 2);
    }
    __syncthreads();  // drains vmcnt -> tiles ready
#pragma unroll
    for (int kk = 0; kk < 64; kk += 32) {
      bf16x8 af[4], bfr[4];
#pragma unroll
      for (int i = 0; i < 4; i++) {
        int ra = wm + i * 16 + l15, rb = wj + i * 16 + l15;
        int cb2 = (kk + quad * 8) * 2;
        af[i]  = *(const bf16x8*)((const char*)As + ra * 128 + (cb2 ^ ((ra & 7) << 4)));
        bfr[i] = *(const bf16x8*)((const char*)Bs + rb * 128 + (cb2 ^ ((rb & 7) << 4)));
      }
#pragma unroll
      for (int i = 0; i < 4; i++)
#pragma unroll
        for (int j = 0; j < 4; j++)
          acc[i][j] = __builtin_amdgcn_mfma_f32_16x16x32_bf16(af[i], bfr[j], acc[i][j], 0, 0, 0);
    }
    __syncthreads();
  }

  float sg[4], bpv[4];
#pragma unroll
  for (int j = 0; j < 4; j++) {
    int gc = bj * 128 + wj + j * 16 + l15;
    sg[j] = 1.f / (1.f + expf(-gate[gc]));
    bpv[j] = bp[gc];
  }
#pragma unroll
  for (int i = 0; i < 4; i++) {
#pragma unroll
    for (int j = 0; j < 4; j++) {
      int gc = bj * 128 + wj + j * 16 + l15;
#pragma unroll
      for (int r = 0; r < 4; r++) {
        int gr = bm * 128 + wm + i * 16 + quad * 4 + r;
        size_t idx = (size_t)gr * DIM + gc;
        out[idx] = x[idx] + sg[j] * (acc[i][j][r] + bpv[j]);
      }
    }
  }
}

extern "C" void kernel_launch(void* const* d_in, const int* in_sizes, int n_in,
                              void* d_out, int out_size, void* d_ws, size_t ws_size,
                              hipStream_t stream) {
  const float* x       = (const float*)d_in[0];
  const float* anchors = (const float*)d_in[1];
  const float* ln_g    = (const float*)d_in[2];
  const float* ln_b    = (const float*)d_in[3];
  const float* W1      = (const float*)d_in[4];
  const float* b1      = (const float*)d_in[5];
  const float* W2      = (const float*)d_in[6];
  const float* b2      = (const float*)d_in[7];
  const float* cg      = (const float*)d_in[8];
  const float* cb      = (const float*)d_in[9];
  const float* Wp      = (const float*)d_in[10];
  const float* bp      = (const float*)d_in[11];
  const float* gate    = (const float*)d_in[12];

  int N = in_sizes[0] / DIM;  // 32768 tokens

  char* w = (char*)d_ws;
  size_t off = 0;
  __hip_bfloat16* WpT = (__hip_bfloat16*)(w + off);  off += 1 << 20;    // 1 MB
  __hip_bfloat16* W2B = (__hip_bfloat16*)(w + off);  off += 128 << 10;  // 128 KB
  __hip_bfloat16* AnB = (__hip_bfloat16*)(w + off);  off += 32 << 10;   // 32 KB
  __hip_bfloat16* Yb  = (__hip_bfloat16*)(w + off);                     // 32 MB

  kprepall<<<400, 256, 0, stream>>>(anchors, Wp, W2, WpT, W2B, AnB);
  ktoken<<<N / 8, 256, 0, stream>>>(x, AnB, ln_g, ln_b, W1, b1, W2B, b2, cg, cb, Yb);
  kgemm<<<dim3(N / 128, DIM / 128), 256, 0, stream>>>(Yb, WpT, x, bp, gate,
                                                      (float*)d_out);
}